// Round 10
// baseline (193.843 us; speedup 1.0000x reference)
//
#include <hip/hip_runtime.h>

// MultiHeadSelfAttention: B=2, S=2048, E=1024, H=16, Dh=64
// All-bf16-MFMA pipeline, 32x32x16 shape, fp32 accumulate:
//   conv_prep:  merged (R10): blocks 0..4095 transpose W* fp32 [k][n] -> bf16
//               Wt [n][k]; blocks 4096..6143 convert inputs fp32 -> bf16 Xbf.
//               (5 -> 4 launches; ~14us/launch overhead measured from
//               sum-of-kernels vs dur_us gap.)
//   gemm mode0: Xbf @ W{q,k,v} + b -> Qh (pre-scaled 0.125*log2e) / Kh [b,h,s,64],
//               Vt [b,h,64,s]. R8-proven LDS swizzle key (r>>1)&3.
//   attn:       R9 geometry (512 thr, 4 q-waves x 32 rows, 2 kv-waves) with
//               launch_bounds (512,4)->(512,2): R9's VGPR=64 cap caused scratch
//               spills (WRITE_SIZE 15.4MB vs 8.2MB output) that confounded the
//               occupancy experiment. Now spill-free at 4 waves/SIMD.
//   gemm mode1: Ctx @ Wo + bo -> d_out fp32

#define QSCALE 0.18033688011112042f  // 0.125 * log2(e)

using bf16x8 = __attribute__((ext_vector_type(8))) short;
using f32x16 = __attribute__((ext_vector_type(16))) float;
using u16x8  = __attribute__((ext_vector_type(8))) unsigned short;

__device__ __forceinline__ unsigned short f2bf(float f) {
  unsigned int u = __float_as_uint(f);
  u += 0x7fffu + ((u >> 16) & 1u);   // round-to-nearest-even
  return (unsigned short)(u >> 16);
}

// async 16B/lane global->LDS; lds dest = wave-uniform base + lane*16
__device__ __forceinline__ void gload_lds16(const unsigned short* g, unsigned short* l) {
  __builtin_amdgcn_global_load_lds(
      (const __attribute__((address_space(1))) unsigned int*)g,
      (__attribute__((address_space(3))) unsigned int*)l, 16, 0, 0);
}

// ------- merged prep: W transpose->bf16 (blocks 0..4095) | x->bf16 (4096..6143)
__global__ void conv_prep_kernel(const float* __restrict__ x, unsigned short* __restrict__ y,
                                 const float* __restrict__ W0, const float* __restrict__ W1,
                                 const float* __restrict__ W2, const float* __restrict__ W3,
                                 unsigned short* __restrict__ out) {
  __shared__ float t[32][33];
  int blk = blockIdx.x;
  if (blk >= 4096) {
    // conv_x: 8 elems/thread
    int i = (blk - 4096) * 256 + threadIdx.x;
    const float4* xf = (const float4*)x;
    float4 a = xf[i * 2], b = xf[i * 2 + 1];
    u16x8 o;
    o[0] = f2bf(a.x); o[1] = f2bf(a.y); o[2] = f2bf(a.z); o[3] = f2bf(a.w);
    o[4] = f2bf(b.x); o[5] = f2bf(b.y); o[6] = f2bf(b.z); o[7] = f2bf(b.w);
    *((u16x8*)y + i) = o;
    return;
  }
  // conv_wT: 32x32 tile transpose, 4 weights
  int z = blk >> 10, rem = blk & 1023;
  const float* W = (z == 0) ? W0 : (z == 1) ? W1 : (z == 2) ? W2 : W3;
  unsigned short* o = out + (size_t)z * 1024 * 1024;
  int kt = (rem >> 5) * 32, nt = (rem & 31) * 32;
  int tx = threadIdx.x & 31, ty = threadIdx.x >> 5;  // 32 x 8
#pragma unroll
  for (int i = 0; i < 4; ++i)
    t[ty + i * 8][tx] = W[(size_t)(kt + ty + i * 8) * 1024 + nt + tx];
  __syncthreads();
#pragma unroll
  for (int i = 0; i < 4; ++i)
    o[(size_t)(nt + ty + i * 8) * 1024 + kt + tx] = f2bf(t[tx][ty + i * 8]);
}

// ---------------- bf16 GEMM, C = A @ Bt^T, K=1024, 128x128 tile -------------
// BK=32, double-buffered async staging, one barrier per K-iter.
// LDS swizzle: physical slot s of row r holds chunk s ^ ((r>>1)&3) (R8-proven).
__global__ __launch_bounds__(256) void gemm_bt_kernel(
    const unsigned short* __restrict__ A, const unsigned short* __restrict__ Bt,
    int mode, const float* __restrict__ bias0, const float* __restrict__ bias1,
    const float* __restrict__ bias2, unsigned short* __restrict__ Qh,
    unsigned short* __restrict__ Kh, unsigned short* __restrict__ Vt,
    float* __restrict__ Out) {
  const int K = 1024;
  __shared__ unsigned short SMEM[16384];       // 32KB: As[2] | Bs[2] (4096 elems each)

  int n0 = blockIdx.x * 128, m0 = blockIdx.y * 128;
  int tid = threadIdx.x;
  int w = tid >> 6, lane = tid & 63, l31 = lane & 31, half = lane >> 5;
  int wm = w >> 1, wn = w & 1;

  f32x16 acc[2][2];
#pragma unroll
  for (int i = 0; i < 2; ++i)
#pragma unroll
    for (int j = 0; j < 2; ++j)
#pragma unroll
      for (int r = 0; r < 16; ++r) acc[i][j][r] = 0.f;

  int srow = lane >> 2;                       // 0..15
  int gchunk = (lane & 3) ^ ((srow >> 1) & 3);  // swizzle key (r>>1)&3 in global chunk
  const unsigned short* Ag = A + (size_t)(m0 + 32 * w + srow) * K + gchunk * 8;
  const unsigned short* Bg = Bt + (size_t)(n0 + 32 * w + srow) * K + gchunk * 8;
  unsigned short* Asw = &SMEM[w * 1024];           // + buf*4096
  unsigned short* Bsw = &SMEM[8192 + w * 1024];

#pragma unroll
  for (int j = 0; j < 2; ++j) {
    gload_lds16(Ag + (size_t)(16 * j) * K, Asw + j * 512);
    gload_lds16(Bg + (size_t)(16 * j) * K, Bsw + j * 512);
  }

  for (int it = 0; it < 32; ++it) {
    int cur = (it & 1) * 4096;
    __syncthreads();                     // drains vmcnt -> buf[cur] visible
    if (it + 1 < 32) {
      int nxt = ((it + 1) & 1) * 4096;
      int kk = (it + 1) * 32;
#pragma unroll
      for (int j = 0; j < 2; ++j) {
        gload_lds16(Ag + kk + (size_t)(16 * j) * K, Asw + nxt + j * 512);
        gload_lds16(Bg + kk + (size_t)(16 * j) * K, Bsw + nxt + j * 512);
      }
    }
    const unsigned short* Asl = &SMEM[cur];
    const unsigned short* Bsl = &SMEM[8192 + cur];
#pragma unroll
    for (int kc = 0; kc < 2; ++kc) {
      int swk = (l31 >> 1) & 3;          // read-side key matches staging
      int ph = ((kc * 2 + half) ^ swk) * 8;
      bf16x8 af[2], bfr[2];
#pragma unroll
      for (int mt = 0; mt < 2; ++mt)
        af[mt] = *(bf16x8*)&Asl[(wm * 64 + mt * 32 + l31) * 32 + ph];
#pragma unroll
      for (int nt = 0; nt < 2; ++nt)
        bfr[nt] = *(bf16x8*)&Bsl[(wn * 64 + nt * 32 + l31) * 32 + ph];
#pragma unroll
      for (int mt = 0; mt < 2; ++mt)
#pragma unroll
        for (int nt = 0; nt < 2; ++nt)
          acc[mt][nt] = __builtin_amdgcn_mfma_f32_32x32x16_bf16(af[mt], bfr[nt], acc[mt][nt], 0, 0, 0);
    }
  }

  if (mode == 1) {
#pragma unroll
    for (int mt = 0; mt < 2; ++mt)
#pragma unroll
      for (int nt = 0; nt < 2; ++nt)
#pragma unroll
        for (int r = 0; r < 16; ++r) {
          int row = (r & 3) + 8 * (r >> 2) + 4 * half;
          int gm = m0 + wm * 64 + mt * 32 + row;
          int gn = n0 + wn * 64 + nt * 32 + l31;
          Out[(size_t)gm * 1024 + gn] = acc[mt][nt][r] + bias0[gn];
        }
    return;
  }

  int btype = blockIdx.x >> 3;   // 0=Q, 1=K, 2=V (uniform per block)
  if (btype < 2) {
    const float* bp = btype ? bias1 : bias0;
    unsigned short* dst = btype ? Kh : Qh;
    float sc = btype ? 1.0f : QSCALE;
#pragma unroll
    for (int mt = 0; mt < 2; ++mt)
#pragma unroll
      for (int nt = 0; nt < 2; ++nt)
#pragma unroll
        for (int r = 0; r < 16; ++r) {
          int row = (r & 3) + 8 * (r >> 2) + 4 * half;
          int gm = m0 + wm * 64 + mt * 32 + row;
          int gn = n0 + wn * 64 + nt * 32 + l31;
          int e = gn & 1023;
          float v = (acc[mt][nt][r] + bp[e]) * sc;
          int hh = e >> 6, d = e & 63;
          int bb = gm >> 11, s = gm & 2047;
          dst[(((size_t)(bb * 16 + hh)) * 2048 + s) * 64 + d] = f2bf(v);
        }
  } else {
    // V: transpose C through LDS, store Vt [b,h,64,2048] coalesced.
    __syncthreads();             // all waves done reading K-loop LDS
    unsigned short* T = SMEM;    // 128(d) x 128(s), swizzled: s' = s ^ ((d&15)<<3)
#pragma unroll
    for (int mt = 0; mt < 2; ++mt)
#pragma unroll
      for (int nt = 0; nt < 2; ++nt)
#pragma unroll
        for (int r = 0; r < 16; ++r) {
          int row = (r & 3) + 8 * (r >> 2) + 4 * half;
          int sl = wm * 64 + mt * 32 + row;            // local s
          int dl = wn * 64 + nt * 32 + l31;            // local d (0..127)
          int e = (n0 - 2048) + dl;
          float v = acc[mt][nt][r] + bias2[e];
          T[dl * 128 + (sl ^ ((dl & 15) << 3))] = f2bf(v);
        }
    __syncthreads();
    int bb = m0 >> 11, s0 = m0 & 2047;
    int h0 = (n0 - 2048) >> 6;
    int rr0 = tid >> 2, csub = tid & 3;
#pragma unroll
    for (int pass = 0; pass < 2; ++pass) {
      int rr = rr0 + 64 * pass;                        // d-row 0..127
      int hh = h0 + (rr >> 6), d = rr & 63;
      unsigned short* vrow = Vt + (((size_t)(bb * 16 + hh)) * 64 + d) * 2048 + s0;
#pragma unroll
      for (int c = 0; c < 4; ++c) {
        int cc = c * 4 + csub;                         // 16B chunk 0..15
        uint4 val = *(uint4*)&T[rr * 128 + ((cc ^ (rr & 15)) * 8)];
        *(uint4*)&vrow[cc * 8] = val;
      }
    }
  }
}

// ---------------- flash attention: 512-thr block, 32 q-rows/wave ------------
// R9 geometry; ONLY change: launch_bounds (512,4)->(512,2) to lift the 64-VGPR
// cap that caused scratch spills. LDS (64KB) still gives 2 blocks/CU x 8 waves
// = 4 waves/SIMD. XCD-bijective grid; R6/R8-proven softmax.
__global__ __launch_bounds__(512, 2) void attn_kernel(
    const unsigned short* __restrict__ Qh, const unsigned short* __restrict__ Kh,
    const unsigned short* __restrict__ Vt, unsigned short* __restrict__ Ctx) {
  __shared__ __align__(16) unsigned short SM[32768];  // 64KB: buf{0,1} x (Ks0|Ks1|Vs0|Vs1)

  // XCD-bijective decode: bx = xcd + 8*(qt + 16*g), bh = g*8 + xcd.
  int bx = blockIdx.x;
  int xcd = bx & 7, tt = bx >> 3;           // tt 0..63
  int qt = tt & 15;
  int bhi = (tt >> 4) * 8 + xcd;            // 0..31
  int h = bhi & 15, b = bhi >> 4;

  int tid = threadIdx.x;
  int w = tid >> 6, lane = tid & 63, l31 = lane & 31, half = lane >> 5;
  int l7 = l31 & 7;
  int mw = w & 3, kw = w >> 2;

  size_t bh = (size_t)bhi;
  const unsigned short* Qb  = Qh + (bh * 2048 + (size_t)qt * 128) * 64;
  const unsigned short* Kbh = Kh + bh * 131072;
  const unsigned short* Vbh = Vt + bh * 131072;

  // Q B-frags: lane holds Q[q = mw*32+l31][k = kc*16 + half*8 + j]
  bf16x8 qf[4];
#pragma unroll
  for (int kc = 0; kc < 4; ++kc)
    qf[kc] = *(const bf16x8*)&Qb[(size_t)(mw * 32 + l31) * 64 + kc * 16 + half * 8];

  // staging: 32 wave-instrs/iter; wave w issues j=0..3, seg g = w*4+j.
  // tile t = g>>3 (0:K h0, 1:K h1, 2:V h0, 3:V h1), s = g&7 (8 rows each).
  // lane -> row s*8 + (lane>>3), global chunk (lane&7) ^ (lane>>3)
  int r8 = lane >> 3, cl = lane & 7, gc = cl ^ r8;
  const unsigned short* gb[4];
  int lofs[4], gstep[4];
#pragma unroll
  for (int j = 0; j < 4; ++j) {
    int g = w * 4 + j, t = g >> 3, s = g & 7;
    if (t < 2) { gb[j] = Kbh + (size_t)(t * 1024 + s * 8 + r8) * 64 + gc * 8; gstep[j] = 4096; }
    else       { gb[j] = Vbh + (size_t)(s * 8 + r8) * 2048 + (t - 2) * 1024 + gc * 8; gstep[j] = 64; }
    lofs[j] = t * 4096 + s * 512;
  }
  // prologue: stage iter 0 into buf 0
#pragma unroll
  for (int j = 0; j < 4; ++j) { gload_lds16(gb[j], SM + lofs[j]); gb[j] += gstep[j]; }

  f32x16 o0, o1;
#pragma unroll
  for (int r = 0; r < 16; ++r) { o0[r] = 0.f; o1[r] = 0.f; }
  float l_acc = 0.f;

  // sum-only softmax (exp2 domain, raw v_exp_f32), RNE pack, permlane exchange
  auto smx = [&](const f32x16& sa, const f32x16& sb, float& lacc, bf16x8* U) {
    float pa[16], pb[16];
#pragma unroll
    for (int r = 0; r < 16; ++r) {
      pa[r] = __builtin_amdgcn_exp2f(sa[r]);
      pb[r] = __builtin_amdgcn_exp2f(sb[r]);
    }
    float t0 = 0.f, t1 = 0.f, t2 = 0.f, t3 = 0.f;
#pragma unroll
    for (int r = 0; r < 16; r += 4) {
      t0 += pa[r] + pb[r]; t1 += pa[r + 1] + pb[r + 1];
      t2 += pa[r + 2] + pb[r + 2]; t3 += pa[r + 3] + pb[r + 3];
    }
    lacc += (t0 + t1) + (t2 + t3);
    unsigned int own[16];
#pragma unroll
    for (int m = 0; m < 4; ++m)
#pragma unroll
      for (int p = 0; p < 2; ++p) {
        int r = 4 * m + 2 * p;
        unsigned int wa, wb;
        asm("v_cvt_pk_bf16_f32 %0, %1, %2" : "=v"(wa) : "v"(pa[r]), "v"(pa[r + 1]));
        asm("v_cvt_pk_bf16_f32 %0, %1, %2" : "=v"(wb) : "v"(pb[r]), "v"(pb[r + 1]));
        own[2 * m + p] = wa;
        own[2 * m + 8 + p] = wb;
      }
#pragma unroll
    for (int kc = 0; kc < 4; ++kc) {
      unsigned int a0 = own[4 * kc],     b0 = own[4 * kc + 2];
      unsigned int a1 = own[4 * kc + 1], b1 = own[4 * kc + 3];
      asm("v_permlane32_swap_b32 %0, %1" : "+v"(a0), "+v"(b0));
      asm("v_permlane32_swap_b32 %0, %1" : "+v"(a1), "+v"(b1));
      union { unsigned int u[4]; bf16x8 v; } Uu;
      Uu.u[0] = a0; Uu.u[1] = a1; Uu.u[2] = b0; Uu.u[3] = b1;
      U[kc] = Uu.v;
    }
  };

  for (int i = 0; i < 16; ++i) {
    __syncthreads();                       // drains vmcnt -> buf[i&1] visible
    if (i < 15) {
      unsigned short* nb = SM + (((i + 1) & 1) << 14);
#pragma unroll
      for (int j = 0; j < 4; ++j) { gload_lds16(gb[j], nb + lofs[j]); gb[j] += gstep[j]; }
    }
    const unsigned short* cur = SM + ((i & 1) << 14);
    const unsigned short* Ksw = cur + kw * 4096;
    const unsigned short* Vsw = cur + 8192 + kw * 4096;

    // S^T = K . Q^T : lane owns column q=l31
    f32x16 st0, st1;
#pragma unroll
    for (int r = 0; r < 16; ++r) { st0[r] = 0.f; st1[r] = 0.f; }
    __builtin_amdgcn_s_setprio(1);
#pragma unroll
    for (int kc = 0; kc < 4; ++kc) {
      int ph = ((kc * 2 + half) ^ l7) * 8;
      bf16x8 kb0 = *(bf16x8*)&Ksw[l31 * 64 + ph];
      bf16x8 kb1 = *(bf16x8*)&Ksw[(32 + l31) * 64 + ph];
      st0 = __builtin_amdgcn_mfma_f32_32x32x16_bf16(kb0, qf[kc], st0, 0, 0, 0);
      st1 = __builtin_amdgcn_mfma_f32_32x32x16_bf16(kb1, qf[kc], st1, 0, 0, 0);
    }
    __builtin_amdgcn_s_setprio(0);

    bf16x8 U[4];
    smx(st0, st1, l_acc, U);

    // O += P . V
    __builtin_amdgcn_s_setprio(1);
#pragma unroll
    for (int kc = 0; kc < 4; ++kc) {
      int ph = ((kc * 2 + half) ^ l7) * 8;
      bf16x8 vb0 = *(bf16x8*)&Vsw[l31 * 64 + ph];
      bf16x8 vb1 = *(bf16x8*)&Vsw[(32 + l31) * 64 + ph];
      o0 = __builtin_amdgcn_mfma_f32_32x32x16_bf16(U[kc], vb0, o0, 0, 0, 0);
      o1 = __builtin_amdgcn_mfma_f32_32x32x16_bf16(U[kc], vb1, o1, 0, 0, 0);
    }
    __builtin_amdgcn_s_setprio(0);
  }

  // merge kv halves (waves w and w^4 share q rows), normalize, store
  float lw = l_acc + __shfl_xor(l_acc, 32);
  __syncthreads();                          // K-loop LDS reads done; reuse SM
  float* mrgO = (float*)SM;                 // [4 mw][64 lane][32 reg] swizzled
  float* mrgL = (float*)SM + 8192;          // [4][32]
  if (kw == 1) {
    float* dst = mrgO + mw * 2048 + lane * 32;
#pragma unroll
    for (int c = 0; c < 8; ++c) {
      float4 t;
      if (c < 4) t = make_float4(o0[4 * c], o0[4 * c + 1], o0[4 * c + 2], o0[4 * c + 3]);
      else       t = make_float4(o1[4 * (c - 4)], o1[4 * (c - 4) + 1], o1[4 * (c - 4) + 2], o1[4 * (c - 4) + 3]);
      *(float4*)&dst[(c ^ l7) * 4] = t;
    }
    if (half == 0) mrgL[mw * 32 + l31] = lw;
  }
  __syncthreads();
  if (kw == 0) {
    const float* src = mrgO + mw * 2048 + lane * 32;
#pragma unroll
    for (int c = 0; c < 8; ++c) {
      float4 t = *(const float4*)&src[(c ^ l7) * 4];
      if (c < 4) { o0[4 * c] += t.x; o0[4 * c + 1] += t.y; o0[4 * c + 2] += t.z; o0[4 * c + 3] += t.w; }
      else       { o1[4 * (c - 4)] += t.x; o1[4 * (c - 4) + 1] += t.y; o1[4 * (c - 4) + 2] += t.z; o1[4 * (c - 4) + 3] += t.w; }
    }
    lw += mrgL[mw * 32 + l31];
    float inv = 1.0f / lw;                 // RNE pack -> exact 1/l
#pragma unroll
    for (int r = 0; r < 16; ++r) {
      int rmap = (r & 3) + 8 * (r >> 2) + 4 * half;
      float invr = __shfl(inv, rmap);
      size_t row = (size_t)(b * 2048 + qt * 128 + mw * 32 + rmap);
      Ctx[row * 1024 + h * 64 + l31]      = f2bf(o0[r] * invr);
      Ctx[row * 1024 + h * 64 + 32 + l31] = f2bf(o1[r] * invr);
    }
  }
}

// ---------------------------------------------------------------------------
extern "C" void kernel_launch(void* const* d_in, const int* in_sizes, int n_in,
                              void* d_out, int out_size, void* d_ws, size_t ws_size,
                              hipStream_t stream) {
  const float* X  = (const float*)d_in[0];
  const float* Wq = (const float*)d_in[1];
  const float* bq = (const float*)d_in[2];
  const float* Wk = (const float*)d_in[3];
  const float* bk = (const float*)d_in[4];
  const float* Wv = (const float*)d_in[5];
  const float* bv = (const float*)d_in[6];
  const float* Wo = (const float*)d_in[7];
  const float* bo = (const float*)d_in[8];

  if (ws_size < (size_t)48 * 1024 * 1024) return;

  char* ws = (char*)d_ws;
  unsigned short* Xbf = (unsigned short*)(ws);
  unsigned short* Wt  = (unsigned short*)(ws + ((size_t)8 << 20));
  unsigned short* Qh  = (unsigned short*)(ws + ((size_t)16 << 20));
  unsigned short* Kh  = (unsigned short*)(ws + ((size_t)24 << 20));
  unsigned short* Vt  = (unsigned short*)(ws + ((size_t)32 << 20));
  unsigned short* Ctx = (unsigned short*)(ws + ((size_t)40 << 20));
  unsigned short* WtO = Wt + (size_t)3 * 1024 * 1024;

  conv_prep_kernel<<<6144, 256, 0, stream>>>(X, Xbf, Wq, Wk, Wv, Wo, Wt);
  gemm_bt_kernel<<<dim3(24, 32), 256, 0, stream>>>(Xbf, Wt, 0, bq, bk, bv, Qh, Kh, Vt, nullptr);
  attn_kernel<<<dim3(512), 512, 0, stream>>>(Qh, Kh, Vt, Ctx);
  gemm_bt_kernel<<<dim3(8, 32), 256, 0, stream>>>(Ctx, WtO, 1, bo, bo, bo, nullptr, nullptr, nullptr, (float*)d_out);
}

// Round 11
// 188.635 us; speedup vs baseline: 1.0276x; 1.0276x over previous
//
#include <hip/hip_runtime.h>

// MultiHeadSelfAttention: B=2, S=2048, E=1024, H=16, Dh=64
// All-bf16-MFMA pipeline, 32x32x16 shape, fp32 accumulate:
//   conv_prep:  merged: blocks 0..4095 transpose W* fp32 -> bf16 Wt [n][k];
//               blocks 4096..6143 convert inputs fp32 -> bf16 Xbf.
//   gemm mode0: Xbf @ W{q,k,v} + b -> Qh (pre-scaled 0.125*log2e) / Kh [b,h,s,64],
//               Vt [b,h,64,s]. R8-proven LDS swizzle key (r>>1)&3.
//               R11: XCD m-stripe grouping (numerics-free block remap): each XCD
//               owns 4 contiguous m-stripes -> per-XCD L2 set 14MB -> 7MB.
//   attn:       R8-GREEN 256-thr kernel VERBATIM (48.4us, system-best 188.5).
//               512-thr occupancy experiments (R9/R10) falsified: lockstep
//               barrier chain is structural; R9's spills polluted L2 (+6us rest).
//   gemm mode1: Ctx @ Wo + bo -> d_out fp32 (same remap)

#define QSCALE 0.18033688011112042f  // 0.125 * log2(e)

using bf16x8 = __attribute__((ext_vector_type(8))) short;
using f32x16 = __attribute__((ext_vector_type(16))) float;
using u16x8  = __attribute__((ext_vector_type(8))) unsigned short;

__device__ __forceinline__ unsigned short f2bf(float f) {
  unsigned int u = __float_as_uint(f);
  u += 0x7fffu + ((u >> 16) & 1u);   // round-to-nearest-even
  return (unsigned short)(u >> 16);
}

// async 16B/lane global->LDS; lds dest = wave-uniform base + lane*16
__device__ __forceinline__ void gload_lds16(const unsigned short* g, unsigned short* l) {
  __builtin_amdgcn_global_load_lds(
      (const __attribute__((address_space(1))) unsigned int*)g,
      (__attribute__((address_space(3))) unsigned int*)l, 16, 0, 0);
}

// ------- merged prep: W transpose->bf16 (blocks 0..4095) | x->bf16 (4096..6143)
__global__ void conv_prep_kernel(const float* __restrict__ x, unsigned short* __restrict__ y,
                                 const float* __restrict__ W0, const float* __restrict__ W1,
                                 const float* __restrict__ W2, const float* __restrict__ W3,
                                 unsigned short* __restrict__ out) {
  __shared__ float t[32][33];
  int blk = blockIdx.x;
  if (blk >= 4096) {
    int i = (blk - 4096) * 256 + threadIdx.x;
    const float4* xf = (const float4*)x;
    float4 a = xf[i * 2], b = xf[i * 2 + 1];
    u16x8 o;
    o[0] = f2bf(a.x); o[1] = f2bf(a.y); o[2] = f2bf(a.z); o[3] = f2bf(a.w);
    o[4] = f2bf(b.x); o[5] = f2bf(b.y); o[6] = f2bf(b.z); o[7] = f2bf(b.w);
    *((u16x8*)y + i) = o;
    return;
  }
  int z = blk >> 10, rem = blk & 1023;
  const float* W = (z == 0) ? W0 : (z == 1) ? W1 : (z == 2) ? W2 : W3;
  unsigned short* o = out + (size_t)z * 1024 * 1024;
  int kt = (rem >> 5) * 32, nt = (rem & 31) * 32;
  int tx = threadIdx.x & 31, ty = threadIdx.x >> 5;  // 32 x 8
#pragma unroll
  for (int i = 0; i < 4; ++i)
    t[ty + i * 8][tx] = W[(size_t)(kt + ty + i * 8) * 1024 + nt + tx];
  __syncthreads();
#pragma unroll
  for (int i = 0; i < 4; ++i)
    o[(size_t)(nt + ty + i * 8) * 1024 + kt + tx] = f2bf(t[tx][ty + i * 8]);
}

// ---------------- bf16 GEMM, C = A @ Bt^T, K=1024, 128x128 tile -------------
// BK=32, double-buffered async staging, one barrier per K-iter.
// LDS swizzle key (r>>1)&3 (R8-proven). R11: XCD m-stripe grouping remap —
// id = by*nx+bx; xcd = id&7; pos = id>>3; bxr = pos>>2; byr = xcd*4 + (pos&3).
// Bijective for nx*ny in {768, 256} with ny=32; pure permutation, numerics-free.
__global__ __launch_bounds__(256) void gemm_bt_kernel(
    const unsigned short* __restrict__ A, const unsigned short* __restrict__ Bt,
    int mode, const float* __restrict__ bias0, const float* __restrict__ bias1,
    const float* __restrict__ bias2, unsigned short* __restrict__ Qh,
    unsigned short* __restrict__ Kh, unsigned short* __restrict__ Vt,
    float* __restrict__ Out) {
  const int K = 1024;
  __shared__ unsigned short SMEM[16384];       // 32KB: As[2] | Bs[2] (4096 elems each)

  int id = blockIdx.y * gridDim.x + blockIdx.x;
  int xcd = id & 7, pos = id >> 3;
  int bxr = pos >> 2, byr = xcd * 4 + (pos & 3);
  int n0 = bxr * 128, m0 = byr * 128;
  int tid = threadIdx.x;
  int w = tid >> 6, lane = tid & 63, l31 = lane & 31, half = lane >> 5;
  int wm = w >> 1, wn = w & 1;

  f32x16 acc[2][2];
#pragma unroll
  for (int i = 0; i < 2; ++i)
#pragma unroll
    for (int j = 0; j < 2; ++j)
#pragma unroll
      for (int r = 0; r < 16; ++r) acc[i][j][r] = 0.f;

  int srow = lane >> 2;                       // 0..15
  int gchunk = (lane & 3) ^ ((srow >> 1) & 3);  // swizzle key (r>>1)&3 in global chunk
  const unsigned short* Ag = A + (size_t)(m0 + 32 * w + srow) * K + gchunk * 8;
  const unsigned short* Bg = Bt + (size_t)(n0 + 32 * w + srow) * K + gchunk * 8;
  unsigned short* Asw = &SMEM[w * 1024];           // + buf*4096
  unsigned short* Bsw = &SMEM[8192 + w * 1024];

#pragma unroll
  for (int j = 0; j < 2; ++j) {
    gload_lds16(Ag + (size_t)(16 * j) * K, Asw + j * 512);
    gload_lds16(Bg + (size_t)(16 * j) * K, Bsw + j * 512);
  }

  for (int it = 0; it < 32; ++it) {
    int cur = (it & 1) * 4096;
    __syncthreads();                     // drains vmcnt -> buf[cur] visible
    if (it + 1 < 32) {
      int nxt = ((it + 1) & 1) * 4096;
      int kk = (it + 1) * 32;
#pragma unroll
      for (int j = 0; j < 2; ++j) {
        gload_lds16(Ag + kk + (size_t)(16 * j) * K, Asw + nxt + j * 512);
        gload_lds16(Bg + kk + (size_t)(16 * j) * K, Bsw + nxt + j * 512);
      }
    }
    const unsigned short* Asl = &SMEM[cur];
    const unsigned short* Bsl = &SMEM[8192 + cur];
#pragma unroll
    for (int kc = 0; kc < 2; ++kc) {
      int swk = (l31 >> 1) & 3;          // read-side key matches staging
      int ph = ((kc * 2 + half) ^ swk) * 8;
      bf16x8 af[2], bfr[2];
#pragma unroll
      for (int mt = 0; mt < 2; ++mt)
        af[mt] = *(bf16x8*)&Asl[(wm * 64 + mt * 32 + l31) * 32 + ph];
#pragma unroll
      for (int nt = 0; nt < 2; ++nt)
        bfr[nt] = *(bf16x8*)&Bsl[(wn * 64 + nt * 32 + l31) * 32 + ph];
#pragma unroll
      for (int mt = 0; mt < 2; ++mt)
#pragma unroll
        for (int nt = 0; nt < 2; ++nt)
          acc[mt][nt] = __builtin_amdgcn_mfma_f32_32x32x16_bf16(af[mt], bfr[nt], acc[mt][nt], 0, 0, 0);
    }
  }

  if (mode == 1) {
#pragma unroll
    for (int mt = 0; mt < 2; ++mt)
#pragma unroll
      for (int nt = 0; nt < 2; ++nt)
#pragma unroll
        for (int r = 0; r < 16; ++r) {
          int row = (r & 3) + 8 * (r >> 2) + 4 * half;
          int gm = m0 + wm * 64 + mt * 32 + row;
          int gn = n0 + wn * 64 + nt * 32 + l31;
          Out[(size_t)gm * 1024 + gn] = acc[mt][nt][r] + bias0[gn];
        }
    return;
  }

  int btype = bxr >> 3;   // 0=Q, 1=K, 2=V (uniform per block)
  if (btype < 2) {
    const float* bp = btype ? bias1 : bias0;
    unsigned short* dst = btype ? Kh : Qh;
    float sc = btype ? 1.0f : QSCALE;
#pragma unroll
    for (int mt = 0; mt < 2; ++mt)
#pragma unroll
      for (int nt = 0; nt < 2; ++nt)
#pragma unroll
        for (int r = 0; r < 16; ++r) {
          int row = (r & 3) + 8 * (r >> 2) + 4 * half;
          int gm = m0 + wm * 64 + mt * 32 + row;
          int gn = n0 + wn * 64 + nt * 32 + l31;
          int e = gn & 1023;
          float v = (acc[mt][nt][r] + bp[e]) * sc;
          int hh = e >> 6, d = e & 63;
          int bb = gm >> 11, s = gm & 2047;
          dst[(((size_t)(bb * 16 + hh)) * 2048 + s) * 64 + d] = f2bf(v);
        }
  } else {
    // V: transpose C through LDS, store Vt [b,h,64,2048] coalesced.
    __syncthreads();             // all waves done reading K-loop LDS
    unsigned short* T = SMEM;    // 128(d) x 128(s), swizzled: s' = s ^ ((d&15)<<3)
#pragma unroll
    for (int mt = 0; mt < 2; ++mt)
#pragma unroll
      for (int nt = 0; nt < 2; ++nt)
#pragma unroll
        for (int r = 0; r < 16; ++r) {
          int row = (r & 3) + 8 * (r >> 2) + 4 * half;
          int sl = wm * 64 + mt * 32 + row;            // local s
          int dl = wn * 64 + nt * 32 + l31;            // local d (0..127)
          int e = (n0 - 2048) + dl;
          float v = acc[mt][nt][r] + bias2[e];
          T[dl * 128 + (sl ^ ((dl & 15) << 3))] = f2bf(v);
        }
    __syncthreads();
    int bb = m0 >> 11, s0 = m0 & 2047;
    int h0 = (n0 - 2048) >> 6;
    int rr0 = tid >> 2, csub = tid & 3;
#pragma unroll
    for (int pass = 0; pass < 2; ++pass) {
      int rr = rr0 + 64 * pass;                        // d-row 0..127
      int hh = h0 + (rr >> 6), d = rr & 63;
      unsigned short* vrow = Vt + (((size_t)(bb * 16 + hh)) * 64 + d) * 2048 + s0;
#pragma unroll
      for (int c = 0; c < 4; ++c) {
        int cc = c * 4 + csub;                         // 16B chunk 0..15
        uint4 val = *(uint4*)&T[rr * 128 + ((cc ^ (rr & 15)) * 8)];
        *(uint4*)&vrow[cc * 8] = val;
      }
    }
  }
}

// ---------------- flash attention: 256-thr block, 64 q-rows/wave ------------
// R8-GREEN kernel VERBATIM. XCD-bijective 1-D grid.
// waves: mw = w&1 (q rows mw*64..+63 of a 128-row q tile), kw = w>>1 (kv half).
// Per iter: 4 tiles (K half0/1, V half0/1) of 64x64 bf16, wave w stages tile w
// (8 segs), XOR swizzle folded into per-lane global chunk. One barrier/iter.
// S^T = K.Q^T for TWO 32-row q-groups sharing the K/V LDS frags. P pack:
// v_cvt_pk_bf16_f32 (RNE) + v_permlane32_swap_b32 cross-half exchange.
__global__ __launch_bounds__(256, 2) void attn_kernel(
    const unsigned short* __restrict__ Qh, const unsigned short* __restrict__ Kh,
    const unsigned short* __restrict__ Vt, unsigned short* __restrict__ Ctx) {
  __shared__ __align__(16) unsigned short SM[32768];  // 64KB: buf{0,1} x (Ks0|Ks1|Vs0|Vs1)

  // XCD-bijective decode: bx = xcd + 8*(qt + 16*g), bh = g*8 + xcd.
  int bx = blockIdx.x;
  int xcd = bx & 7, tt = bx >> 3;           // tt 0..63
  int qt = tt & 15;
  int bhi = (tt >> 4) * 8 + xcd;            // 0..31
  int h = bhi & 15, b = bhi >> 4;

  int tid = threadIdx.x;
  int w = tid >> 6, lane = tid & 63, l31 = lane & 31, half = lane >> 5;
  int l7 = l31 & 7;
  int mw = w & 1, kw = w >> 1;

  size_t bh = (size_t)bhi;
  const unsigned short* Qb  = Qh + (bh * 2048 + (size_t)qt * 128) * 64;
  const unsigned short* Kbh = Kh + bh * 131072;
  const unsigned short* Vbh = Vt + bh * 131072;

  // Q B-frags: lane holds Q[q = mw*64 + qg*32 + l31][k = kc*16 + half*8 + j]
  bf16x8 qf0[4], qf1[4];
#pragma unroll
  for (int kc = 0; kc < 4; ++kc) {
    qf0[kc] = *(const bf16x8*)&Qb[(size_t)(mw * 64 + l31) * 64 + kc * 16 + half * 8];
    qf1[kc] = *(const bf16x8*)&Qb[(size_t)(mw * 64 + 32 + l31) * 64 + kc * 16 + half * 8];
  }

  // staging: wave w owns tile t=w (0/1: K seq-half, 2/3: V seq-half), 8 segs x 8 rows.
  int r8 = lane >> 3, gc = (lane & 7) ^ r8;
  const unsigned short* gbase;
  int gstep; size_t segstep;
  if (w < 2) { gbase = Kbh + (size_t)(w * 1024 + r8) * 64 + gc * 8; gstep = 4096; segstep = 512; }
  else       { gbase = Vbh + (size_t)r8 * 2048 + (w - 2) * 1024 + gc * 8; gstep = 64; segstep = 16384; }
  unsigned short* lb = SM + w * 4096;   // seg j at + j*512; buffer1 at +16384

  // prologue: stage iter 0 into buf 0
#pragma unroll
  for (int j = 0; j < 8; ++j) gload_lds16(gbase + j * segstep, lb + j * 512);
  gbase += gstep;

  f32x16 o00, o01, o10, o11;
#pragma unroll
  for (int r = 0; r < 16; ++r) { o00[r] = 0.f; o01[r] = 0.f; o10[r] = 0.f; o11[r] = 0.f; }
  float l0 = 0.f, l1 = 0.f;

  for (int i = 0; i < 16; ++i) {
    __syncthreads();                       // drains vmcnt -> buf[i&1] visible
    if (i < 15) {
      unsigned short* nb = lb + (((i + 1) & 1) << 14);
#pragma unroll
      for (int j = 0; j < 8; ++j) gload_lds16(gbase + j * segstep, nb + j * 512);
      gbase += gstep;
    }
    const unsigned short* cur = SM + ((i & 1) << 14);
    const unsigned short* Ksw = cur + kw * 4096;
    const unsigned short* Vsw = cur + 8192 + kw * 4096;

    // S^T = K . Q^T : both q-groups share kb frags (4 indep MFMA chains)
    f32x16 s00, s01, s10, s11;
#pragma unroll
    for (int r = 0; r < 16; ++r) { s00[r] = 0.f; s01[r] = 0.f; s10[r] = 0.f; s11[r] = 0.f; }
    __builtin_amdgcn_s_setprio(1);
#pragma unroll
    for (int kc = 0; kc < 4; ++kc) {
      int ph = ((kc * 2 + half) ^ l7) * 8;
      bf16x8 kb0 = *(bf16x8*)&Ksw[l31 * 64 + ph];
      bf16x8 kb1 = *(bf16x8*)&Ksw[(32 + l31) * 64 + ph];
      s00 = __builtin_amdgcn_mfma_f32_32x32x16_bf16(kb0, qf0[kc], s00, 0, 0, 0);
      s01 = __builtin_amdgcn_mfma_f32_32x32x16_bf16(kb1, qf0[kc], s01, 0, 0, 0);
      s10 = __builtin_amdgcn_mfma_f32_32x32x16_bf16(kb0, qf1[kc], s10, 0, 0, 0);
      s11 = __builtin_amdgcn_mfma_f32_32x32x16_bf16(kb1, qf1[kc], s11, 0, 0, 0);
    }
    __builtin_amdgcn_s_setprio(0);

    // sum-only softmax (exp2 domain, raw v_exp_f32), RNE pack, VALU exchange
    bf16x8 U0[4], U1[4];
    auto smx = [&](const f32x16& sa, const f32x16& sb, float& lacc, bf16x8* U) {
      float pa[16], pb[16];
#pragma unroll
      for (int r = 0; r < 16; ++r) {
        pa[r] = __builtin_amdgcn_exp2f(sa[r]);
        pb[r] = __builtin_amdgcn_exp2f(sb[r]);
      }
      float t0 = 0.f, t1 = 0.f, t2 = 0.f, t3 = 0.f;
#pragma unroll
      for (int r = 0; r < 16; r += 4) {
        t0 += pa[r] + pb[r]; t1 += pa[r + 1] + pb[r + 1];
        t2 += pa[r + 2] + pb[r + 2]; t3 += pa[r + 3] + pb[r + 3];
      }
      lacc += (t0 + t1) + (t2 + t3);
      unsigned int own[16];
#pragma unroll
      for (int m = 0; m < 4; ++m)
#pragma unroll
        for (int p = 0; p < 2; ++p) {
          int r = 4 * m + 2 * p;
          unsigned int wa, wb;
          asm("v_cvt_pk_bf16_f32 %0, %1, %2" : "=v"(wa) : "v"(pa[r]), "v"(pa[r + 1]));
          asm("v_cvt_pk_bf16_f32 %0, %1, %2" : "=v"(wb) : "v"(pb[r]), "v"(pb[r + 1]));
          own[2 * m + p] = wa;
          own[2 * m + 8 + p] = wb;
        }
#pragma unroll
      for (int kc = 0; kc < 4; ++kc) {
        unsigned int a0 = own[4 * kc],     b0 = own[4 * kc + 2];
        unsigned int a1 = own[4 * kc + 1], b1 = own[4 * kc + 3];
        asm("v_permlane32_swap_b32 %0, %1" : "+v"(a0), "+v"(b0));
        asm("v_permlane32_swap_b32 %0, %1" : "+v"(a1), "+v"(b1));
        union { unsigned int u[4]; bf16x8 v; } Uu;
        Uu.u[0] = a0; Uu.u[1] = a1; Uu.u[2] = b0; Uu.u[3] = b1;
        U[kc] = Uu.v;
      }
    };
    smx(s00, s01, l0, U0);
    smx(s10, s11, l1, U1);

    // O += P . V : both q-groups share vb frags
    __builtin_amdgcn_s_setprio(1);
#pragma unroll
    for (int kc = 0; kc < 4; ++kc) {
      int ph = ((kc * 2 + half) ^ l7) * 8;
      bf16x8 vb0 = *(bf16x8*)&Vsw[l31 * 64 + ph];
      bf16x8 vb1 = *(bf16x8*)&Vsw[(32 + l31) * 64 + ph];
      o00 = __builtin_amdgcn_mfma_f32_32x32x16_bf16(U0[kc], vb0, o00, 0, 0, 0);
      o01 = __builtin_amdgcn_mfma_f32_32x32x16_bf16(U0[kc], vb1, o01, 0, 0, 0);
      o10 = __builtin_amdgcn_mfma_f32_32x32x16_bf16(U1[kc], vb0, o10, 0, 0, 0);
      o11 = __builtin_amdgcn_mfma_f32_32x32x16_bf16(U1[kc], vb1, o11, 0, 0, 0);
    }
    __builtin_amdgcn_s_setprio(0);
  }

  // merge kv halves (waves w and w^2 share q rows), normalize, store
  float lw0 = l0 + __shfl_xor(l0, 32);
  float lw1 = l1 + __shfl_xor(l1, 32);
  __syncthreads();                          // K-loop LDS reads done; reuse SM
  float* mrgO = (float*)SM;                 // [2 mw][2 qg][64 lane][32 reg] swizzled
  float* mrgL = (float*)SM + 8192;          // [4][32]
  if (kw == 1) {
    auto dump = [&](const f32x16& a0, const f32x16& a1, float lw, int qg) {
      float* dst = mrgO + (mw * 2 + qg) * 2048 + lane * 32;
#pragma unroll
      for (int c = 0; c < 8; ++c) {
        float4 t;
        if (c < 4) t = make_float4(a0[4 * c], a0[4 * c + 1], a0[4 * c + 2], a0[4 * c + 3]);
        else       t = make_float4(a1[4 * (c - 4)], a1[4 * (c - 4) + 1], a1[4 * (c - 4) + 2], a1[4 * (c - 4) + 3]);
        *(float4*)&dst[(c ^ l7) * 4] = t;
      }
      if (half == 0) mrgL[(mw * 2 + qg) * 32 + l31] = lw;
    };
    dump(o00, o01, lw0, 0);
    dump(o10, o11, lw1, 1);
  }
  __syncthreads();
  if (kw == 0) {
    auto fin = [&](f32x16& a0, f32x16& a1, float lw, int qg) {
      const float* src = mrgO + (mw * 2 + qg) * 2048 + lane * 32;
#pragma unroll
      for (int c = 0; c < 8; ++c) {
        float4 t = *(const float4*)&src[(c ^ l7) * 4];
        if (c < 4) { a0[4 * c] += t.x; a0[4 * c + 1] += t.y; a0[4 * c + 2] += t.z; a0[4 * c + 3] += t.w; }
        else       { a1[4 * (c - 4)] += t.x; a1[4 * (c - 4) + 1] += t.y; a1[4 * (c - 4) + 2] += t.z; a1[4 * (c - 4) + 3] += t.w; }
      }
      lw += mrgL[(mw * 2 + qg) * 32 + l31];
      float inv = 1.0f / lw;                 // RNE pack -> exact 1/l
#pragma unroll
      for (int r = 0; r < 16; ++r) {
        int rmap = (r & 3) + 8 * (r >> 2) + 4 * half;
        float invr = __shfl(inv, rmap);
        size_t row = (size_t)(b * 2048 + qt * 128 + mw * 64 + qg * 32 + rmap);
        Ctx[row * 1024 + h * 64 + l31]      = f2bf(a0[r] * invr);
        Ctx[row * 1024 + h * 64 + 32 + l31] = f2bf(a1[r] * invr);
      }
    };
    fin(o00, o01, lw0, 0);
    fin(o10, o11, lw1, 1);
  }
}

// ---------------------------------------------------------------------------
extern "C" void kernel_launch(void* const* d_in, const int* in_sizes, int n_in,
                              void* d_out, int out_size, void* d_ws, size_t ws_size,
                              hipStream_t stream) {
  const float* X  = (const float*)d_in[0];
  const float* Wq = (const float*)d_in[1];
  const float* bq = (const float*)d_in[2];
  const float* Wk = (const float*)d_in[3];
  const float* bk = (const float*)d_in[4];
  const float* Wv = (const float*)d_in[5];
  const float* bv = (const float*)d_in[6];
  const float* Wo = (const float*)d_in[7];
  const float* bo = (const float*)d_in[8];

  if (ws_size < (size_t)48 * 1024 * 1024) return;

  char* ws = (char*)d_ws;
  unsigned short* Xbf = (unsigned short*)(ws);
  unsigned short* Wt  = (unsigned short*)(ws + ((size_t)8 << 20));
  unsigned short* Qh  = (unsigned short*)(ws + ((size_t)16 << 20));
  unsigned short* Kh  = (unsigned short*)(ws + ((size_t)24 << 20));
  unsigned short* Vt  = (unsigned short*)(ws + ((size_t)32 << 20));
  unsigned short* Ctx = (unsigned short*)(ws + ((size_t)40 << 20));
  unsigned short* WtO = Wt + (size_t)3 * 1024 * 1024;

  conv_prep_kernel<<<6144, 256, 0, stream>>>(X, Xbf, Wq, Wk, Wv, Wo, Wt);
  gemm_bt_kernel<<<dim3(24, 32), 256, 0, stream>>>(Xbf, Wt, 0, bq, bk, bv, Qh, Kh, Vt, nullptr);
  attn_kernel<<<dim3(512), 256, 0, stream>>>(Qh, Kh, Vt, Ctx);
  gemm_bt_kernel<<<dim3(8, 32), 256, 0, stream>>>(Ctx, WtO, 1, bo, bo, bo, nullptr, nullptr, nullptr, (float*)d_out);
}

// Round 12
// 180.578 us; speedup vs baseline: 1.0735x; 1.0446x over previous
//
#include <hip/hip_runtime.h>

// MultiHeadSelfAttention: B=2, S=2048, E=1024, H=16, Dh=64
// All-bf16-MFMA pipeline, 32x32x16 shape, fp32 accumulate:
//   conv_prep:  merged: blocks 0..4095 transpose W* fp32 -> bf16 Wt [n][k];
//               blocks 4096..6143 convert inputs fp32 -> bf16 Xbf.
//   gemm mode0: Xbf @ W{q,k,v} + b -> Qh (pre-scaled 0.125*log2e) / Kh [b,h,s,64],
//               Vt [b,h,64,s]. R8 LDS swizzle key (r>>1)&3; R11 XCD m-stripe remap.
//   attn:       R12: QBLK=256 (512 thr, 4 m-waves x 64 q-rows of R8's exact
//               2-qg inner body, 2 kv-waves). K/V staging per block unchanged
//               -> staging instrs + L2 traffic HALVE per unit work (256->128 MB).
//               Grid 256 (1 block/CU, 8 waves = same 2 waves/SIMD as R8).
//               Merge epilogue two-phased (8 slots > 64KB LDS if single-phase).
//   gemm mode1: Ctx @ Wo + bo -> d_out fp32

#define QSCALE 0.18033688011112042f  // 0.125 * log2(e)

using bf16x8 = __attribute__((ext_vector_type(8))) short;
using f32x16 = __attribute__((ext_vector_type(16))) float;
using u16x8  = __attribute__((ext_vector_type(8))) unsigned short;

__device__ __forceinline__ unsigned short f2bf(float f) {
  unsigned int u = __float_as_uint(f);
  u += 0x7fffu + ((u >> 16) & 1u);   // round-to-nearest-even
  return (unsigned short)(u >> 16);
}

// async 16B/lane global->LDS; lds dest = wave-uniform base + lane*16
__device__ __forceinline__ void gload_lds16(const unsigned short* g, unsigned short* l) {
  __builtin_amdgcn_global_load_lds(
      (const __attribute__((address_space(1))) unsigned int*)g,
      (__attribute__((address_space(3))) unsigned int*)l, 16, 0, 0);
}

// ------- merged prep: W transpose->bf16 (blocks 0..4095) | x->bf16 (4096..6143)
__global__ void conv_prep_kernel(const float* __restrict__ x, unsigned short* __restrict__ y,
                                 const float* __restrict__ W0, const float* __restrict__ W1,
                                 const float* __restrict__ W2, const float* __restrict__ W3,
                                 unsigned short* __restrict__ out) {
  __shared__ float t[32][33];
  int blk = blockIdx.x;
  if (blk >= 4096) {
    int i = (blk - 4096) * 256 + threadIdx.x;
    const float4* xf = (const float4*)x;
    float4 a = xf[i * 2], b = xf[i * 2 + 1];
    u16x8 o;
    o[0] = f2bf(a.x); o[1] = f2bf(a.y); o[2] = f2bf(a.z); o[3] = f2bf(a.w);
    o[4] = f2bf(b.x); o[5] = f2bf(b.y); o[6] = f2bf(b.z); o[7] = f2bf(b.w);
    *((u16x8*)y + i) = o;
    return;
  }
  int z = blk >> 10, rem = blk & 1023;
  const float* W = (z == 0) ? W0 : (z == 1) ? W1 : (z == 2) ? W2 : W3;
  unsigned short* o = out + (size_t)z * 1024 * 1024;
  int kt = (rem >> 5) * 32, nt = (rem & 31) * 32;
  int tx = threadIdx.x & 31, ty = threadIdx.x >> 5;  // 32 x 8
#pragma unroll
  for (int i = 0; i < 4; ++i)
    t[ty + i * 8][tx] = W[(size_t)(kt + ty + i * 8) * 1024 + nt + tx];
  __syncthreads();
#pragma unroll
  for (int i = 0; i < 4; ++i)
    o[(size_t)(nt + ty + i * 8) * 1024 + kt + tx] = f2bf(t[tx][ty + i * 8]);
}

// ---------------- bf16 GEMM, C = A @ Bt^T, K=1024, 128x128 tile -------------
// BK=32, double-buffered async staging, one barrier per K-iter.
// LDS swizzle key (r>>1)&3 (R8-proven). R11 XCD m-stripe remap (kept, neutral).
__global__ __launch_bounds__(256) void gemm_bt_kernel(
    const unsigned short* __restrict__ A, const unsigned short* __restrict__ Bt,
    int mode, const float* __restrict__ bias0, const float* __restrict__ bias1,
    const float* __restrict__ bias2, unsigned short* __restrict__ Qh,
    unsigned short* __restrict__ Kh, unsigned short* __restrict__ Vt,
    float* __restrict__ Out) {
  const int K = 1024;
  __shared__ unsigned short SMEM[16384];       // 32KB: As[2] | Bs[2] (4096 elems each)

  int id = blockIdx.y * gridDim.x + blockIdx.x;
  int xcd = id & 7, pos = id >> 3;
  int bxr = pos >> 2, byr = xcd * 4 + (pos & 3);
  int n0 = bxr * 128, m0 = byr * 128;
  int tid = threadIdx.x;
  int w = tid >> 6, lane = tid & 63, l31 = lane & 31, half = lane >> 5;
  int wm = w >> 1, wn = w & 1;

  f32x16 acc[2][2];
#pragma unroll
  for (int i = 0; i < 2; ++i)
#pragma unroll
    for (int j = 0; j < 2; ++j)
#pragma unroll
      for (int r = 0; r < 16; ++r) acc[i][j][r] = 0.f;

  int srow = lane >> 2;                       // 0..15
  int gchunk = (lane & 3) ^ ((srow >> 1) & 3);  // swizzle key (r>>1)&3 in global chunk
  const unsigned short* Ag = A + (size_t)(m0 + 32 * w + srow) * K + gchunk * 8;
  const unsigned short* Bg = Bt + (size_t)(n0 + 32 * w + srow) * K + gchunk * 8;
  unsigned short* Asw = &SMEM[w * 1024];           // + buf*4096
  unsigned short* Bsw = &SMEM[8192 + w * 1024];

#pragma unroll
  for (int j = 0; j < 2; ++j) {
    gload_lds16(Ag + (size_t)(16 * j) * K, Asw + j * 512);
    gload_lds16(Bg + (size_t)(16 * j) * K, Bsw + j * 512);
  }

  for (int it = 0; it < 32; ++it) {
    int cur = (it & 1) * 4096;
    __syncthreads();                     // drains vmcnt -> buf[cur] visible
    if (it + 1 < 32) {
      int nxt = ((it + 1) & 1) * 4096;
      int kk = (it + 1) * 32;
#pragma unroll
      for (int j = 0; j < 2; ++j) {
        gload_lds16(Ag + kk + (size_t)(16 * j) * K, Asw + nxt + j * 512);
        gload_lds16(Bg + kk + (size_t)(16 * j) * K, Bsw + nxt + j * 512);
      }
    }
    const unsigned short* Asl = &SMEM[cur];
    const unsigned short* Bsl = &SMEM[8192 + cur];
#pragma unroll
    for (int kc = 0; kc < 2; ++kc) {
      int swk = (l31 >> 1) & 3;          // read-side key matches staging
      int ph = ((kc * 2 + half) ^ swk) * 8;
      bf16x8 af[2], bfr[2];
#pragma unroll
      for (int mt = 0; mt < 2; ++mt)
        af[mt] = *(bf16x8*)&Asl[(wm * 64 + mt * 32 + l31) * 32 + ph];
#pragma unroll
      for (int nt = 0; nt < 2; ++nt)
        bfr[nt] = *(bf16x8*)&Bsl[(wn * 64 + nt * 32 + l31) * 32 + ph];
#pragma unroll
      for (int mt = 0; mt < 2; ++mt)
#pragma unroll
        for (int nt = 0; nt < 2; ++nt)
          acc[mt][nt] = __builtin_amdgcn_mfma_f32_32x32x16_bf16(af[mt], bfr[nt], acc[mt][nt], 0, 0, 0);
    }
  }

  if (mode == 1) {
#pragma unroll
    for (int mt = 0; mt < 2; ++mt)
#pragma unroll
      for (int nt = 0; nt < 2; ++nt)
#pragma unroll
        for (int r = 0; r < 16; ++r) {
          int row = (r & 3) + 8 * (r >> 2) + 4 * half;
          int gm = m0 + wm * 64 + mt * 32 + row;
          int gn = n0 + wn * 64 + nt * 32 + l31;
          Out[(size_t)gm * 1024 + gn] = acc[mt][nt][r] + bias0[gn];
        }
    return;
  }

  int btype = bxr >> 3;   // 0=Q, 1=K, 2=V (uniform per block)
  if (btype < 2) {
    const float* bp = btype ? bias1 : bias0;
    unsigned short* dst = btype ? Kh : Qh;
    float sc = btype ? 1.0f : QSCALE;
#pragma unroll
    for (int mt = 0; mt < 2; ++mt)
#pragma unroll
      for (int nt = 0; nt < 2; ++nt)
#pragma unroll
        for (int r = 0; r < 16; ++r) {
          int row = (r & 3) + 8 * (r >> 2) + 4 * half;
          int gm = m0 + wm * 64 + mt * 32 + row;
          int gn = n0 + wn * 64 + nt * 32 + l31;
          int e = gn & 1023;
          float v = (acc[mt][nt][r] + bp[e]) * sc;
          int hh = e >> 6, d = e & 63;
          int bb = gm >> 11, s = gm & 2047;
          dst[(((size_t)(bb * 16 + hh)) * 2048 + s) * 64 + d] = f2bf(v);
        }
  } else {
    // V: transpose C through LDS, store Vt [b,h,64,2048] coalesced.
    __syncthreads();             // all waves done reading K-loop LDS
    unsigned short* T = SMEM;    // 128(d) x 128(s), swizzled: s' = s ^ ((d&15)<<3)
#pragma unroll
    for (int mt = 0; mt < 2; ++mt)
#pragma unroll
      for (int nt = 0; nt < 2; ++nt)
#pragma unroll
        for (int r = 0; r < 16; ++r) {
          int row = (r & 3) + 8 * (r >> 2) + 4 * half;
          int sl = wm * 64 + mt * 32 + row;            // local s
          int dl = wn * 64 + nt * 32 + l31;            // local d (0..127)
          int e = (n0 - 2048) + dl;
          float v = acc[mt][nt][r] + bias2[e];
          T[dl * 128 + (sl ^ ((dl & 15) << 3))] = f2bf(v);
        }
    __syncthreads();
    int bb = m0 >> 11, s0 = m0 & 2047;
    int h0 = (n0 - 2048) >> 6;
    int rr0 = tid >> 2, csub = tid & 3;
#pragma unroll
    for (int pass = 0; pass < 2; ++pass) {
      int rr = rr0 + 64 * pass;                        // d-row 0..127
      int hh = h0 + (rr >> 6), d = rr & 63;
      unsigned short* vrow = Vt + (((size_t)(bb * 16 + hh)) * 64 + d) * 2048 + s0;
#pragma unroll
      for (int c = 0; c < 4; ++c) {
        int cc = c * 4 + csub;                         // 16B chunk 0..15
        uint4 val = *(uint4*)&T[rr * 128 + ((cc ^ (rr & 15)) * 8)];
        *(uint4*)&vrow[cc * 8] = val;
      }
    }
  }
}

// ---------------- flash attention: 512-thr block, QBLK=256 ------------------
// R12: 4 m-waves (mw = w&3, 64 q-rows each: 2 qg of 32 -- R8's exact inner
// body) x 2 kv-waves (kw = w>>2). K/V tiles + LDS layout identical to R8;
// each tile now staged by 2 waves x 4 segs (32 gloads/block = half the per-CU
// staging of R8's 2-block config for the same MFMA work).
// Grid 256, XCD-bijective: bx = xcd + 8*(qt + 8*g), bh = g*8 + xcd, qt 0..7.
// Merge epilogue two-phased over mw-pairs (LDS cap).
__global__ __launch_bounds__(512, 2) void attn_kernel(
    const unsigned short* __restrict__ Qh, const unsigned short* __restrict__ Kh,
    const unsigned short* __restrict__ Vt, unsigned short* __restrict__ Ctx) {
  __shared__ __align__(16) unsigned short SM[32768];  // 64KB: buf{0,1} x (Ks0|Ks1|Vs0|Vs1)

  int bx = blockIdx.x;
  int xcd = bx & 7, tt = bx >> 3;           // tt 0..31
  int qt = tt & 7;
  int bhi = (tt >> 3) * 8 + xcd;            // 0..31
  int h = bhi & 15, b = bhi >> 4;

  int tid = threadIdx.x;
  int w = tid >> 6, lane = tid & 63, l31 = lane & 31, half = lane >> 5;
  int l7 = l31 & 7;
  int mw = w & 3, kw = w >> 2;

  size_t bh = (size_t)bhi;
  const unsigned short* Qb  = Qh + (bh * 2048 + (size_t)qt * 256) * 64;
  const unsigned short* Kbh = Kh + bh * 131072;
  const unsigned short* Vbh = Vt + bh * 131072;

  // Q B-frags: lane holds Q[q = mw*64 + qg*32 + l31][k = kc*16 + half*8 + j]
  bf16x8 qf0[4], qf1[4];
#pragma unroll
  for (int kc = 0; kc < 4; ++kc) {
    qf0[kc] = *(const bf16x8*)&Qb[(size_t)(mw * 64 + l31) * 64 + kc * 16 + half * 8];
    qf1[kc] = *(const bf16x8*)&Qb[(size_t)(mw * 64 + 32 + l31) * 64 + kc * 16 + half * 8];
  }

  // staging: wave w stages tile t = w>>1 (0/1: K seq-half, 2/3: V seq-half),
  // segs s = (w&1)*4 + j, j=0..3. Layout per tile identical to R8.
  int r8 = lane >> 3, gc = (lane & 7) ^ r8;
  int t = w >> 1, s0 = (w & 1) * 4;
  const unsigned short* gb[4];
  int lofs[4];
  int gstep;
#pragma unroll
  for (int j = 0; j < 4; ++j) {
    int s = s0 + j;
    if (t < 2) { gb[j] = Kbh + (size_t)(t * 1024 + s * 8 + r8) * 64 + gc * 8; }
    else       { gb[j] = Vbh + (size_t)(s * 8 + r8) * 2048 + (t - 2) * 1024 + gc * 8; }
    lofs[j] = t * 4096 + s * 512;
  }
  gstep = (t < 2) ? 4096 : 64;

  // prologue: stage iter 0 into buf 0
#pragma unroll
  for (int j = 0; j < 4; ++j) { gload_lds16(gb[j], SM + lofs[j]); gb[j] += gstep; }

  f32x16 o00, o01, o10, o11;
#pragma unroll
  for (int r = 0; r < 16; ++r) { o00[r] = 0.f; o01[r] = 0.f; o10[r] = 0.f; o11[r] = 0.f; }
  float l0 = 0.f, l1 = 0.f;

  for (int i = 0; i < 16; ++i) {
    __syncthreads();                       // drains vmcnt -> buf[i&1] visible
    if (i < 15) {
      unsigned short* nb = SM + (((i + 1) & 1) << 14);
#pragma unroll
      for (int j = 0; j < 4; ++j) { gload_lds16(gb[j], nb + lofs[j]); gb[j] += gstep; }
    }
    const unsigned short* cur = SM + ((i & 1) << 14);
    const unsigned short* Ksw = cur + kw * 4096;
    const unsigned short* Vsw = cur + 8192 + kw * 4096;

    // S^T = K . Q^T : both q-groups share kb frags (4 indep MFMA chains)
    f32x16 s00, s01, s10, s11;
#pragma unroll
    for (int r = 0; r < 16; ++r) { s00[r] = 0.f; s01[r] = 0.f; s10[r] = 0.f; s11[r] = 0.f; }
    __builtin_amdgcn_s_setprio(1);
#pragma unroll
    for (int kc = 0; kc < 4; ++kc) {
      int ph = ((kc * 2 + half) ^ l7) * 8;
      bf16x8 kb0 = *(bf16x8*)&Ksw[l31 * 64 + ph];
      bf16x8 kb1 = *(bf16x8*)&Ksw[(32 + l31) * 64 + ph];
      s00 = __builtin_amdgcn_mfma_f32_32x32x16_bf16(kb0, qf0[kc], s00, 0, 0, 0);
      s01 = __builtin_amdgcn_mfma_f32_32x32x16_bf16(kb1, qf0[kc], s01, 0, 0, 0);
      s10 = __builtin_amdgcn_mfma_f32_32x32x16_bf16(kb0, qf1[kc], s10, 0, 0, 0);
      s11 = __builtin_amdgcn_mfma_f32_32x32x16_bf16(kb1, qf1[kc], s11, 0, 0, 0);
    }
    __builtin_amdgcn_s_setprio(0);

    // sum-only softmax (exp2 domain, raw v_exp_f32), RNE pack, VALU exchange
    bf16x8 U0[4], U1[4];
    auto smx = [&](const f32x16& sa, const f32x16& sb, float& lacc, bf16x8* U) {
      float pa[16], pb[16];
#pragma unroll
      for (int r = 0; r < 16; ++r) {
        pa[r] = __builtin_amdgcn_exp2f(sa[r]);
        pb[r] = __builtin_amdgcn_exp2f(sb[r]);
      }
      float t0 = 0.f, t1 = 0.f, t2 = 0.f, t3 = 0.f;
#pragma unroll
      for (int r = 0; r < 16; r += 4) {
        t0 += pa[r] + pb[r]; t1 += pa[r + 1] + pb[r + 1];
        t2 += pa[r + 2] + pb[r + 2]; t3 += pa[r + 3] + pb[r + 3];
      }
      lacc += (t0 + t1) + (t2 + t3);
      unsigned int own[16];
#pragma unroll
      for (int m = 0; m < 4; ++m)
#pragma unroll
        for (int p = 0; p < 2; ++p) {
          int r = 4 * m + 2 * p;
          unsigned int wa, wb;
          asm("v_cvt_pk_bf16_f32 %0, %1, %2" : "=v"(wa) : "v"(pa[r]), "v"(pa[r + 1]));
          asm("v_cvt_pk_bf16_f32 %0, %1, %2" : "=v"(wb) : "v"(pb[r]), "v"(pb[r + 1]));
          own[2 * m + p] = wa;
          own[2 * m + 8 + p] = wb;
        }
#pragma unroll
      for (int kc = 0; kc < 4; ++kc) {
        unsigned int a0 = own[4 * kc],     b0 = own[4 * kc + 2];
        unsigned int a1 = own[4 * kc + 1], b1 = own[4 * kc + 3];
        asm("v_permlane32_swap_b32 %0, %1" : "+v"(a0), "+v"(b0));
        asm("v_permlane32_swap_b32 %0, %1" : "+v"(a1), "+v"(b1));
        union { unsigned int u[4]; bf16x8 v; } Uu;
        Uu.u[0] = a0; Uu.u[1] = a1; Uu.u[2] = b0; Uu.u[3] = b1;
        U[kc] = Uu.v;
      }
    };
    smx(s00, s01, l0, U0);
    smx(s10, s11, l1, U1);

    // O += P . V : both q-groups share vb frags
    __builtin_amdgcn_s_setprio(1);
#pragma unroll
    for (int kc = 0; kc < 4; ++kc) {
      int ph = ((kc * 2 + half) ^ l7) * 8;
      bf16x8 vb0 = *(bf16x8*)&Vsw[l31 * 64 + ph];
      bf16x8 vb1 = *(bf16x8*)&Vsw[(32 + l31) * 64 + ph];
      o00 = __builtin_amdgcn_mfma_f32_32x32x16_bf16(U0[kc], vb0, o00, 0, 0, 0);
      o01 = __builtin_amdgcn_mfma_f32_32x32x16_bf16(U0[kc], vb1, o01, 0, 0, 0);
      o10 = __builtin_amdgcn_mfma_f32_32x32x16_bf16(U1[kc], vb0, o10, 0, 0, 0);
      o11 = __builtin_amdgcn_mfma_f32_32x32x16_bf16(U1[kc], vb1, o11, 0, 0, 0);
    }
    __builtin_amdgcn_s_setprio(0);
  }

  // merge kv halves (waves w and w^4 share q rows; kw 0 <-> 1), two phases
  // over mw-pairs (p = mw>>1) since 8 slots exceed the 64KB LDS in one pass.
  float lw0 = l0 + __shfl_xor(l0, 32);
  float lw1 = l1 + __shfl_xor(l1, 32);
  __syncthreads();                          // K-loop LDS reads done; reuse SM
  float* mrgO = (float*)SM;                 // [4 slots][64 lane][32] swizzled (32KB)
  float* mrgL = (float*)SM + 8192;          // [4 slots][32]
  int slot2 = (mw & 1) * 2;                 // slot base for this wave's pair-phase
  int phase = mw >> 1;
#pragma unroll
  for (int p = 0; p < 2; ++p) {
    if (kw == 1 && phase == p) {
      auto dump = [&](const f32x16& a0, const f32x16& a1, float lw, int qg) {
        float* dst = mrgO + (slot2 + qg) * 2048 + lane * 32;
#pragma unroll
        for (int c = 0; c < 8; ++c) {
          float4 t4;
          if (c < 4) t4 = make_float4(a0[4 * c], a0[4 * c + 1], a0[4 * c + 2], a0[4 * c + 3]);
          else       t4 = make_float4(a1[4 * (c - 4)], a1[4 * (c - 4) + 1], a1[4 * (c - 4) + 2], a1[4 * (c - 4) + 3]);
          *(float4*)&dst[(c ^ l7) * 4] = t4;
        }
        if (half == 0) mrgL[(slot2 + qg) * 32 + l31] = lw;
      };
      dump(o00, o01, lw0, 0);
      dump(o10, o11, lw1, 1);
    }
    __syncthreads();
    if (kw == 0 && phase == p) {
      auto fin = [&](f32x16& a0, f32x16& a1, float lw, int qg) {
        const float* src = mrgO + (slot2 + qg) * 2048 + lane * 32;
#pragma unroll
        for (int c = 0; c < 8; ++c) {
          float4 t4 = *(const float4*)&src[(c ^ l7) * 4];
          if (c < 4) { a0[4 * c] += t4.x; a0[4 * c + 1] += t4.y; a0[4 * c + 2] += t4.z; a0[4 * c + 3] += t4.w; }
          else       { a1[4 * (c - 4)] += t4.x; a1[4 * (c - 4) + 1] += t4.y; a1[4 * (c - 4) + 2] += t4.z; a1[4 * (c - 4) + 3] += t4.w; }
        }
        lw += mrgL[(slot2 + qg) * 32 + l31];
        float inv = 1.0f / lw;               // RNE pack -> exact 1/l
#pragma unroll
        for (int r = 0; r < 16; ++r) {
          int rmap = (r & 3) + 8 * (r >> 2) + 4 * half;
          float invr = __shfl(inv, rmap);
          size_t row = (size_t)(b * 2048 + qt * 256 + mw * 64 + qg * 32 + rmap);
          Ctx[row * 1024 + h * 64 + l31]      = f2bf(a0[r] * invr);
          Ctx[row * 1024 + h * 64 + 32 + l31] = f2bf(a1[r] * invr);
        }
      };
      fin(o00, o01, lw0, 0);
      fin(o10, o11, lw1, 1);
    }
    __syncthreads();
  }
}

// ---------------------------------------------------------------------------
extern "C" void kernel_launch(void* const* d_in, const int* in_sizes, int n_in,
                              void* d_out, int out_size, void* d_ws, size_t ws_size,
                              hipStream_t stream) {
  const float* X  = (const float*)d_in[0];
  const float* Wq = (const float*)d_in[1];
  const float* bq = (const float*)d_in[2];
  const float* Wk = (const float*)d_in[3];
  const float* bk = (const float*)d_in[4];
  const float* Wv = (const float*)d_in[5];
  const float* bv = (const float*)d_in[6];
  const float* Wo = (const float*)d_in[7];
  const float* bo = (const float*)d_in[8];

  if (ws_size < (size_t)48 * 1024 * 1024) return;

  char* ws = (char*)d_ws;
  unsigned short* Xbf = (unsigned short*)(ws);
  unsigned short* Wt  = (unsigned short*)(ws + ((size_t)8 << 20));
  unsigned short* Qh  = (unsigned short*)(ws + ((size_t)16 << 20));
  unsigned short* Kh  = (unsigned short*)(ws + ((size_t)24 << 20));
  unsigned short* Vt  = (unsigned short*)(ws + ((size_t)32 << 20));
  unsigned short* Ctx = (unsigned short*)(ws + ((size_t)40 << 20));
  unsigned short* WtO = Wt + (size_t)3 * 1024 * 1024;

  conv_prep_kernel<<<6144, 256, 0, stream>>>(X, Xbf, Wq, Wk, Wv, Wo, Wt);
  gemm_bt_kernel<<<dim3(24, 32), 256, 0, stream>>>(Xbf, Wt, 0, bq, bk, bv, Qh, Kh, Vt, nullptr);
  attn_kernel<<<dim3(256), 512, 0, stream>>>(Qh, Kh, Vt, Ctx);
  gemm_bt_kernel<<<dim3(8, 32), 256, 0, stream>>>(Ctx, WtO, 1, bo, bo, bo, nullptr, nullptr, nullptr, (float*)d_out);
}